// Round 12
// baseline (294.049 us; speedup 1.0000x reference)
//
#include <hip/hip_runtime.h>

#define N_NODES_C 50000
#define FDIM 64
#define EPS_C 1e-5f

#define PARTS 16               // node partitions; 50000/16 = 3125 exact
#define NPP 3125
#define SLICE (3 * NPP)        // 9375 floats = 37.5 KB accumulate-LDS
#define NSHARD 8               // sublists per partition (shard = blockIdx&7)
#define NLIST (PARTS * NSHARD) // 128 sublists
#define SUBCAP 16384           // entries/sublist; mean 12500, sigma~111
#define BUK_BLK 512
#define BUK_GRID 1024          // ~1562 edges/block -> bucket mean 98
#define CAP 160                // LDS bucket capacity (+6.4 sigma, spill-guarded)
#define ACC_BLK 512

typedef float vfloat4 __attribute__((ext_vector_type(4)));

__device__ __forceinline__ void nt_store_f4(float4* p, float x, float y, float z, float w) {
    vfloat4 v = { x, y, z, w };
    __builtin_nontemporal_store(v, (vfloat4*)p);
}

// ---------------------------------------------------------------------------
// Pass A: per-edge partials (unchanged from R8; roofline). Pure dense stream
// of e with normal loads (e allocates in L3 for norm's re-read); nt-store
// the partials.
// ---------------------------------------------------------------------------
__global__ void __launch_bounds__(256)
partial_kernel(const float4* __restrict__ e4, float2* __restrict__ partials,
               int nEdges) {
    const int total = nEdges * 16;
    const int stride = gridDim.x * blockDim.x;   // %16==0 -> groups aligned
    for (int idx = blockIdx.x * blockDim.x + threadIdx.x; idx < total; idx += stride) {
        float4 v = e4[idx];
        float sum = (v.x + v.y) + (v.z + v.w);
        float sq  = (v.x * v.x + v.y * v.y) + (v.z * v.z + v.w * v.w);
#pragma unroll
        for (int m = 1; m < 16; m <<= 1) {
            sum += __shfl_xor(sum, m);
            sq  += __shfl_xor(sq,  m);
        }
        if ((idx & 15) == 0) {
            unsigned long long bits;
            float2 pq = make_float2(sum, sq);
            __builtin_memcpy(&bits, &pq, 8);
            __builtin_nontemporal_store(bits, (unsigned long long*)(partials + (idx >> 4)));
        }
    }
}

// ---------------------------------------------------------------------------
// Pass B1: bucket. Reads ONLY dst+partials (19.2 MB, once), scatters entries
// {local, sum, sq} into per-partition LDS buckets, one batched global flush
// per bucket at kernel end. The 410 MB e-stream is untouched by this
// machinery (R10's mistake corrected).
// ---------------------------------------------------------------------------
__global__ void __launch_bounds__(BUK_BLK)
bucket_kernel(const int* __restrict__ dst, const float2* __restrict__ partials,
              unsigned* __restrict__ locs, float2* __restrict__ vals,
              int* __restrict__ gcnt, int nEdges) {
    __shared__ unsigned bloc[PARTS][CAP];   // 10.2 KB
    __shared__ float2   bval[PARTS][CAP];   // 20.5 KB
    __shared__ int bcnt[PARTS];
    __shared__ int fbase[PARTS];
    const int tid = threadIdx.x;
    if (tid < PARTS) bcnt[tid] = 0;
    __syncthreads();

    const int shard = blockIdx.x & (NSHARD - 1);

#define BK_PUT(D, S, Q)                                                     \
    { int p_ = (D) / NPP;                                                   \
      unsigned l_ = (unsigned)((D) - p_ * NPP);                             \
      int pos_ = atomicAdd(&bcnt[p_], 1);                                   \
      if (pos_ < CAP) { bloc[p_][pos_] = l_; bval[p_][pos_] = make_float2((S), (Q)); } \
      else { int g_ = atomicAdd(&gcnt[p_ * NSHARD + shard], 1);             \
             if (g_ < SUBCAP) { size_t o_ = (size_t)(p_ * NSHARD + shard) * SUBCAP + g_; \
                                locs[o_] = l_; vals[o_] = make_float2((S), (Q)); } } }

    const int step = BUK_GRID * BUK_BLK * 4;
    for (int i0 = (blockIdx.x * BUK_BLK + tid) * 4; i0 < nEdges; i0 += step) {
        if (i0 + 3 < nEdges) {
            int4 d4 = *(const int4*)(dst + i0);
            vfloat4 p01 = __builtin_nontemporal_load((const vfloat4*)(partials + i0));
            vfloat4 p23 = __builtin_nontemporal_load((const vfloat4*)(partials + i0 + 2));
            BK_PUT(d4.x, p01.x, p01.y); BK_PUT(d4.y, p01.z, p01.w);
            BK_PUT(d4.z, p23.x, p23.y); BK_PUT(d4.w, p23.z, p23.w);
        } else {
            for (int i = i0; i < nEdges; ++i) {
                float2 pq = partials[i];
                BK_PUT(dst[i], pq.x, pq.y);
            }
        }
    }
    __syncthreads();

    // batched flush: one global atomic per (bucket, block)
    if (tid < PARTS) fbase[tid] = atomicAdd(&gcnt[tid * NSHARD + shard],
                                            min(bcnt[tid], CAP));
    __syncthreads();
#pragma unroll 4
    for (int q = 0; q < PARTS; ++q) {
        const int c = min(bcnt[q], CAP);
        const int base = fbase[q];
        const size_t o0 = (size_t)(q * NSHARD + shard) * SUBCAP;
        for (int i = tid; i < c; i += BUK_BLK) {
            int g = base + i;
            if (g < SUBCAP) {
                __builtin_nontemporal_store(bloc[q][i], locs + o0 + g);
                unsigned long long bits;
                __builtin_memcpy(&bits, &bval[q][i], 8);
                __builtin_nontemporal_store(bits, (unsigned long long*)(vals + o0 + g));
            }
        }
    }
#undef BK_PUT
}

// ---------------------------------------------------------------------------
// Pass B2: accumulate. One block per sublist: every entry in-range -> 3 LDS
// atomics at 100% lane efficiency; nt-flush the 37.5 KB slice to acc.
// ---------------------------------------------------------------------------
__global__ void __launch_bounds__(ACC_BLK)
accumulate_kernel(const unsigned* __restrict__ locs, const float2* __restrict__ vals,
                  const int* __restrict__ gcnt, float* __restrict__ acc) {
    __shared__ float sm[SLICE];
    const int tid = threadIdx.x;
    for (int i = tid; i < SLICE; i += ACC_BLK) sm[i] = 0.0f;
    __syncthreads();

    const int li  = blockIdx.x;
    const int cnt = min(gcnt[li], SUBCAP);
    const unsigned* __restrict__ sl = locs + (size_t)li * SUBCAP;
    const float2*   __restrict__ sv = vals + (size_t)li * SUBCAP;
    for (int i = tid; i < cnt; i += ACC_BLK) {
        unsigned l = sl[i];
        float2 v = sv[i];
        atomicAdd(&sm[l], v.x);
        atomicAdd(&sm[NPP + l], v.y);
        atomicAdd(&sm[2 * NPP + l], 1.0f);
    }
    __syncthreads();
    float* __restrict__ outp = acc + (size_t)li * SLICE;
    for (int i = tid; i < SLICE; i += ACC_BLK)
        __builtin_nontemporal_store(sm[i], outp + i);
}

// ---------------------------------------------------------------------------
// Pass C: sum the NSHARD copies per partition; mean + 1/(std+eps), (n-1).
// ---------------------------------------------------------------------------
__global__ void __launch_bounds__(256)
reduce_finalize_kernel(const float* __restrict__ acc, float2* __restrict__ stats,
                       int nNodes) {
    int n = blockIdx.x * blockDim.x + threadIdx.x;
    if (n >= nNodes) return;
    int p = n / NPP, local = n - p * NPP;
    const float* bptr = acc + (size_t)(p * NSHARD) * SLICE + local;
    float s = 0.f, q = 0.f, dg = 0.f;
#pragma unroll
    for (int ss = 0; ss < NSHARD; ++ss, bptr += SLICE) {
        s  += __builtin_nontemporal_load(bptr);
        q  += __builtin_nontemporal_load(bptr + NPP);
        dg += __builtin_nontemporal_load(bptr + 2 * NPP);
    }
    float cnt  = dg * (float)FDIM;
    float safe = fmaxf(cnt, 1.0f);
    float mean = s / safe;
    float var  = (q - cnt * mean * mean) / fmaxf(cnt - 1.0f, 1.0f);
    float stdv = sqrtf(fmaxf(var, 0.0f));
    stats[n] = make_float2(mean, 1.0f / (stdv + EPS_C));
}

// ---------------------------------------------------------------------------
// Pass D: normalize (unchanged from R8). Reverse iteration (e's L3-resident
// tail first) + nt stores for out.
// ---------------------------------------------------------------------------
__global__ void __launch_bounds__(256)
norm_kernel(const float4* __restrict__ e4, const int* __restrict__ dst,
            const float2* __restrict__ stats,
            const float4* __restrict__ gamma4, const float4* __restrict__ beta4,
            float4* __restrict__ out4, int nEdges) {
    const int total  = nEdges * 16;
    const int stride = gridDim.x * blockDim.x;   // %16==0
    const int gtid   = blockIdx.x * blockDim.x + threadIdx.x;
    const int sub    = gtid & 15;
    const float4 g = gamma4[sub];
    const float4 b = beta4[sub];
    const int nIter = (total + stride - 1) / stride;
    for (int it = nIter - 1; it >= 0; --it) {
        int idx = it * stride + gtid;
        if (idx >= total) continue;
        float2 mi = stats[dst[idx >> 4]];
        float4 v  = e4[idx];
        nt_store_f4(out4 + idx,
                    g.x * (v.x - mi.x) * mi.y + b.x,
                    g.y * (v.y - mi.x) * mi.y + b.y,
                    g.z * (v.z - mi.x) * mi.y + b.z,
                    g.w * (v.w - mi.x) * mi.y + b.w);
    }
}

extern "C" void kernel_launch(void* const* d_in, const int* in_sizes, int n_in,
                              void* d_out, int out_size, void* d_ws, size_t ws_size,
                              hipStream_t stream) {
    const float* e     = (const float*)d_in[0];
    const float* gamma = (const float*)d_in[1];
    const float* beta  = (const float*)d_in[2];
    const int*   dst   = (const int*)d_in[3];
    const int nEdges = in_sizes[3];
    const int nNodes = N_NODES_C;

    // d_ws layout (~42 MB, matches R5's proven footprint):
    //   partials [E] float2            = 12.8 MB
    //   locs  [NLIST][SUBCAP] u32      =  8.0 MB
    //   vals  [NLIST][SUBCAP] float2   = 16.0 MB
    //   acc   [NLIST][SLICE]  float    =  4.8 MB
    //   stats [N] float2               =  0.4 MB
    //   gcnt  [NLIST] int              =  512 B (memset each call)
    float2*   partials = (float2*)d_ws;
    unsigned* locs  = (unsigned*)(partials + nEdges);
    float2*   vals  = (float2*)(locs + (size_t)NLIST * SUBCAP);
    float*    acc   = (float*)(vals + (size_t)NLIST * SUBCAP);
    float2*   stats = (float2*)(acc + (size_t)NLIST * SLICE);
    int*      gcnt  = (int*)(stats + nNodes);

    hipMemsetAsync(gcnt, 0, NLIST * sizeof(int), stream);

    partial_kernel<<<2048, 256, 0, stream>>>((const float4*)e, partials, nEdges);
    bucket_kernel<<<BUK_GRID, BUK_BLK, 0, stream>>>(dst, partials, locs, vals, gcnt, nEdges);
    accumulate_kernel<<<NLIST, ACC_BLK, 0, stream>>>(locs, vals, gcnt, acc);
    reduce_finalize_kernel<<<(nNodes + 255) / 256, 256, 0, stream>>>(acc, stats, nNodes);
    norm_kernel<<<2048, 256, 0, stream>>>(
        (const float4*)e, dst, stats,
        (const float4*)gamma, (const float4*)beta,
        (float4*)d_out, nEdges);
}

// Round 13
// 249.323 us; speedup vs baseline: 1.1794x; 1.1794x over previous
//
#include <hip/hip_runtime.h>

#define N_NODES_C 50000
#define FDIM 64
#define EPS_C 1e-5f

#define PARTS 16            // 50000/16 = 3125 exact
#define NPP 3125
#define SLICE (3 * NPP)     // 9375 floats = 37.5 KB LDS
#define BPERP 48            // %8==0: all 16 readers of slice b share XCD b%8
#define SCAT_BLK 512
#define SCAT_GRID (PARTS * BPERP)   // 768 = 3 blocks/CU (slack vs 4/CU cap)

typedef float vfloat4 __attribute__((ext_vector_type(4)));

__device__ __forceinline__ void nt_store_f4(float4* p, float x, float y, float z, float w) {
    vfloat4 v = { x, y, z, w };
    __builtin_nontemporal_store(v, (vfloat4*)p);
}

// one edge: conditional LDS-atomic triple
#define EDGE_ACC(D, SV, QV)                                            \
    { unsigned l_ = (unsigned)((D) - lo);                              \
      if (l_ < NPP) { atomicAdd(&sm[l_], (SV));                        \
                      atomicAdd(&sm[NPP + l_], (QV));                  \
                      atomicAdd(&sm[2 * NPP + l_], 1.0f); } }

// ---------------------------------------------------------------------------
// Pass A: per-edge partials. Dense stream of e (normal loads -> e allocates
// in L3 for norm's re-read); nt-store the partials (no reuse pollution).
// ---------------------------------------------------------------------------
__global__ void __launch_bounds__(256)
partial_kernel(const float4* __restrict__ e4, float2* __restrict__ partials,
               int nEdges) {
    const int total = nEdges * 16;
    const int stride = gridDim.x * blockDim.x;   // %16==0 -> groups aligned
    for (int idx = blockIdx.x * blockDim.x + threadIdx.x; idx < total; idx += stride) {
        float4 v = e4[idx];
        float sum = (v.x + v.y) + (v.z + v.w);
        float sq  = (v.x * v.x + v.y * v.y) + (v.z * v.z + v.w * v.w);
#pragma unroll
        for (int m = 1; m < 16; m <<= 1) {
            sum += __shfl_xor(sum, m);
            sq  += __shfl_xor(sq,  m);
        }
        if ((idx & 15) == 0) {
            unsigned long long bits;
            float2 pq = make_float2(sum, sq);
            __builtin_memcpy(&bits, &pq, 8);
            __builtin_nontemporal_store(bits, (unsigned long long*)(partials + (idx >> 4)));
        }
    }
}

// ---------------------------------------------------------------------------
// Pass B: scatter cache-resident partials into partitioned LDS stats.
// blockIdx = p*BPERP + b; BPERP%8==0 -> XCD(bid)=b%8 under round-robin
// dispatch: each XCD holds 6 slices (2.4 MB dst+partials) in its L2, read by
// all 16 partitions. 3 blocks/CU (scheduling slack), 85-VGPR budget.
// ---------------------------------------------------------------------------
__global__ void __launch_bounds__(SCAT_BLK, 6)
scatter_kernel(const int* __restrict__ dst, const float2* __restrict__ partials,
               float* __restrict__ acc, int nEdges) {
    __shared__ float sm[SLICE];
    const int tid = threadIdx.x;
    for (int i = tid; i < SLICE; i += SCAT_BLK) sm[i] = 0.0f;
    __syncthreads();

    const int p  = blockIdx.x / BPERP;
    const int b  = blockIdx.x % BPERP;
    const int lo = p * NPP;

    const int step = BPERP * SCAT_BLK * 4;
    for (int i0 = (b * SCAT_BLK + tid) * 4; i0 < nEdges; i0 += step) {
        if (i0 + 3 < nEdges) {
            int4   d4  = *(const int4*)(dst + i0);
            float4 p01 = *(const float4*)(partials + i0);
            float4 p23 = *(const float4*)(partials + i0 + 2);
            EDGE_ACC(d4.x, p01.x, p01.y); EDGE_ACC(d4.y, p01.z, p01.w);
            EDGE_ACC(d4.z, p23.x, p23.y); EDGE_ACC(d4.w, p23.z, p23.w);
        } else {
            for (int i = i0; i < nEdges; ++i) {
                float2 pq = partials[i];
                EDGE_ACC(dst[i], pq.x, pq.y);
            }
        }
    }
    __syncthreads();
    float* __restrict__ outp = acc + (size_t)blockIdx.x * SLICE;
    for (int i = tid; i < SLICE; i += SCAT_BLK) {
        __builtin_nontemporal_store(sm[i], outp + i);   // no L3 pollution
    }
}

// ---------------------------------------------------------------------------
// Pass C: sum the BPERP per-block copies; mean + 1/(std+eps), unbiased (n-1).
// ---------------------------------------------------------------------------
__global__ void __launch_bounds__(256)
reduce_finalize_kernel(const float* __restrict__ acc, float2* __restrict__ stats,
                       int nNodes) {
    int n = blockIdx.x * blockDim.x + threadIdx.x;
    if (n >= nNodes) return;
    int p = n / NPP, local = n - p * NPP;
    const float* bptr = acc + (size_t)(p * BPERP) * SLICE + local;
    float s = 0.f, q = 0.f, dg = 0.f;
#pragma unroll 8
    for (int bb = 0; bb < BPERP; ++bb, bptr += SLICE) {
        s  += bptr[0];
        q  += bptr[NPP];
        dg += bptr[2 * NPP];
    }
    float cnt  = dg * (float)FDIM;
    float safe = fmaxf(cnt, 1.0f);
    float mean = s / safe;
    float var  = (q - cnt * mean * mean) / fmaxf(cnt - 1.0f, 1.0f);
    float stdv = sqrtf(fmaxf(var, 0.0f));
    stats[n] = make_float2(mean, 1.0f / (stdv + EPS_C));
}

// ---------------------------------------------------------------------------
// Pass D: normalize. Reverse iteration order (read e's L3-resident tail
// first) + nt-stores for out (keep out's 410 MB from evicting e in L3).
// ---------------------------------------------------------------------------
__global__ void __launch_bounds__(256)
norm_kernel(const float4* __restrict__ e4, const int* __restrict__ dst,
            const float2* __restrict__ stats,
            const float4* __restrict__ gamma4, const float4* __restrict__ beta4,
            float4* __restrict__ out4, int nEdges) {
    const int total  = nEdges * 16;
    const int stride = gridDim.x * blockDim.x;   // %16==0
    const int gtid   = blockIdx.x * blockDim.x + threadIdx.x;
    const int sub    = gtid & 15;
    const float4 g = gamma4[sub];
    const float4 b = beta4[sub];
    const int nIter = (total + stride - 1) / stride;
    for (int it = nIter - 1; it >= 0; --it) {
        int idx = it * stride + gtid;
        if (idx >= total) continue;
        float2 mi = stats[dst[idx >> 4]];
        float4 v  = e4[idx];
        nt_store_f4(out4 + idx,
                    g.x * (v.x - mi.x) * mi.y + b.x,
                    g.y * (v.y - mi.x) * mi.y + b.y,
                    g.z * (v.z - mi.x) * mi.y + b.z,
                    g.w * (v.w - mi.x) * mi.y + b.w);
    }
}

extern "C" void kernel_launch(void* const* d_in, const int* in_sizes, int n_in,
                              void* d_out, int out_size, void* d_ws, size_t ws_size,
                              hipStream_t stream) {
    const float* e     = (const float*)d_in[0];
    const float* gamma = (const float*)d_in[1];
    const float* beta  = (const float*)d_in[2];
    const int*   dst   = (const int*)d_in[3];
    const int nEdges = in_sizes[3];
    const int nNodes = N_NODES_C;

    // d_ws layout (all regions fully overwritten every call -> no memset):
    //   acc      [SCAT_GRID][SLICE] = 28.8 MB
    //   stats    [N] float2         =  0.4 MB
    //   partials [E] float2         = 12.8 MB
    float*  acc      = (float*)d_ws;
    float2* stats    = (float2*)(acc + (size_t)SCAT_GRID * SLICE);
    float2* partials = stats + nNodes;

    partial_kernel<<<2048, 256, 0, stream>>>((const float4*)e, partials, nEdges);
    scatter_kernel<<<SCAT_GRID, SCAT_BLK, 0, stream>>>(dst, partials, acc, nEdges);
    reduce_finalize_kernel<<<(nNodes + 255) / 256, 256, 0, stream>>>(acc, stats, nNodes);
    norm_kernel<<<2048, 256, 0, stream>>>(
        (const float4*)e, dst, stats,
        (const float4*)gamma, (const float4*)beta,
        (float4*)d_out, nEdges);
}